// Round 11
// baseline (92.751 us; speedup 1.0000x reference)
//
#include <hip/hip_runtime.h>
#include <hip/hip_bf16.h>

namespace {

constexpr int N = 4096;
constexpr int D = 512;
constexpr int BM = 64;    // tile 64x64, ONE WAVE per tile; 4 tiles/block (R23)
constexpr int BK = 64;    // K-step per fragment column-slice (64 fp8 bytes)
constexpr int KITERS = D / BK;  // 8 per phase
constexpr int NB = N / BM;      // 64 block-rows
constexpr int NBLK = NB * (NB + 1) / 2;  // 2080 upper-tri tiles (= 8 * 260)
constexpr int NGRID = NBLK / 4;          // 520 blocks x 4 waves
constexpr int TILEB = BM * BK;  // 4 KB: one 64-row x 64-byte k-slice
constexpr int PANELB = BM * D;  // 32 KB: one 64-row fp8 panel

// workspace layout (bytes)
constexpr size_t OFF_XB  = 0;                          // fp8 X  [N*D]  fragment-major
constexpr size_t OFF_YB  = (size_t)N * D;              // fp8 Y  [N*D]  fragment-major
constexpr size_t OFF_SQX = OFF_YB + (size_t)N * D;     // fp32 ||x_i||^2 [N]
constexpr size_t OFF_SQY = OFF_SQX + (size_t)N * 4;
constexpr size_t OFF_SX  = OFF_SQY + (size_t)N * 4;    // fp32 row sums KX [N]
constexpr size_t OFF_SY  = OFF_SX + (size_t)N * 4;     // fp32 row sums KY [N]
constexpr size_t OFF_T1  = OFF_SY + (size_t)N * 4;     // fp32 scalar sum(KX*KY)
constexpr size_t WS_NEED = OFF_T1 + 4;

// FRAGMENT-MAJOR ws layout: element (row r, k) of a 64x64B slice lives at
//   nib*1024 + quad*256 + cl*16 + pass*8 + j
// (nib=(r>>4)&3, cl=r&15, quad=(k>>3)&3, pass=k>>5, j=k&7). A fragment
// (16 rows x 64B of K) is a contiguous 1KB at base + lane*16; the 4
// fragments of a 64-row tile sit at +0/+1024/+2048/+3072 -- all reachable
// from ONE address register via the 13-bit offset immediate.
//
// R23: 64x64/WAVE + ASM DEPTH-3 PIPELINE.
// R22b's result (main still ~35us) fit a simple model: per round,
// 4 waves/SIMD x 39cy MFMA = 156cy of compute vs ~600cy batch latency at
// depth-2 -> 26% matrix-pipe util -> 32us. Same model reproduces R17
// (serial loads, 1700cy/step -> 92us). Levers: (1) 32 MFMA per step
// (64x64/wave, half the loads/FLOP), (2) depth-3 (cover = 2 rounds).
// 2 waves/SIMD x 155cy = 310cy/round, 2 rounds = 620 >= latency ->
// util -> MFMA floor. Regs ~210-230 -> 2 waves/SIMD natural; grid 520
// blocks = 2.03/CU supplies exactly that. launch_bounds(256,2): NO reg
// cap (R19/R20: caps cause spill/AGPR disasters).
// vmcnt discipline: 8-load batches; steady state 24 outstanding, wait
// vmcnt(16) = own oldest batch done; epilogue foreign VMEM is FIFO-newer
// -> over-wait only. Tail: vmcnt(8), vmcnt(0).
constexpr float D2_SKIP = 240.f;

typedef __attribute__((ext_vector_type(4))) float floatx4;
typedef __attribute__((ext_vector_type(2))) long longx2;

__device__ inline unsigned short bf16bits(float f) {
  return __builtin_bit_cast(unsigned short, __float2bfloat16(f));
}

// fp32 -> fp8 e4m3 (OCP) conversion into the fragment-major layout + exact
// fp32 row squared norms. One wave per row; lane handles 8 consecutive
// elements -> one 8B store. Also zeroes sX/sY/T1.
__global__ void prep_kernel(const float* __restrict__ X, const float* __restrict__ Y,
                            unsigned char* __restrict__ Xf8, unsigned char* __restrict__ Yf8,
                            float* __restrict__ sqX, float* __restrict__ sqY,
                            float* __restrict__ sX, float* __restrict__ sY,
                            float* __restrict__ T1) {
  const int wave = threadIdx.x >> 6, lane = threadIdx.x & 63;
  const int row = blockIdx.x * 4 + wave;
  const int m = blockIdx.y;
  const float* __restrict__ src = m ? Y : X;
  unsigned char* __restrict__ dst = m ? Yf8 : Xf8;
  float* __restrict__ dsq = m ? sqY : sqX;

  if (threadIdx.x < 4) {
    float* z = m ? sY : sX;
    z[blockIdx.x * 4 + threadIdx.x] = 0.f;
  }
  if (blockIdx.x == 0 && m == 0 && threadIdx.x == 0) *T1 = 0.f;

  const float4* s4 = (const float4*)(src + (size_t)row * D);
  float4 v0 = s4[lane * 2];
  float4 v1 = s4[lane * 2 + 1];
  float acc = v0.x * v0.x + v0.y * v0.y + v0.z * v0.z + v0.w * v0.w
            + v1.x * v1.x + v1.y * v1.y + v1.z * v1.z + v1.w * v1.w;

  unsigned int w0 = 0, w1 = 0;
  w0 = __builtin_amdgcn_cvt_pk_fp8_f32(v0.x, v0.y, w0, false);
  w0 = __builtin_amdgcn_cvt_pk_fp8_f32(v0.z, v0.w, w0, true);
  w1 = __builtin_amdgcn_cvt_pk_fp8_f32(v1.x, v1.y, w1, false);
  w1 = __builtin_amdgcn_cvt_pk_fp8_f32(v1.z, v1.w, w1, true);
  const unsigned long long pk =
      (unsigned long long)w0 | ((unsigned long long)w1 << 32);

  // destination: k = lane*8 .. +8 of this row, fragment-major address
  const int p    = row >> 6;          // 64-row panel
  const int nib  = (row >> 4) & 3;
  const int cl   = row & 15;
  const int ks   = lane >> 3;         // 64-byte k-slice
  const int pass = (lane >> 2) & 1;
  const int quad = lane & 3;
  const size_t off = (size_t)p * PANELB + (size_t)ks * TILEB +
                     nib * 1024 + quad * 256 + cl * 16 + pass * 8;
  *(unsigned long long*)(dst + off) = pk;

#pragma unroll
  for (int mm = 32; mm >= 1; mm >>= 1) acc += __shfl_xor(acc, mm, 64);
  if (lane == 0) dsq[row] = acc;
}

// --- asm pipeline primitives -------------------------------------------
// 8 async 16B loads from two 64-bit VGPR addresses, fragment siblings via
// the offset immediate: A* <- [PA + {0,1K,2K,3K}], B* <- [PB + ...].
#define ISSUE8_(A0, A1, A2, A3, B0, B1, B2, B3, PA, PB)                      \
  asm volatile("global_load_dwordx4 %0, %8, off\n\t"                         \
               "global_load_dwordx4 %1, %8, off offset:1024\n\t"             \
               "global_load_dwordx4 %2, %8, off offset:2048\n\t"             \
               "global_load_dwordx4 %3, %8, off offset:3072\n\t"             \
               "global_load_dwordx4 %4, %9, off\n\t"                         \
               "global_load_dwordx4 %5, %9, off offset:1024\n\t"             \
               "global_load_dwordx4 %6, %9, off offset:2048\n\t"             \
               "global_load_dwordx4 %7, %9, off offset:3072"                 \
               : "=&v"(A0), "=&v"(A1), "=&v"(A2), "=&v"(A3),                 \
                 "=&v"(B0), "=&v"(B1), "=&v"(B2), "=&v"(B3)                  \
               : "v"(PA), "v"(PB)                                            \
               : "memory")
#define ISSUE8(...) ISSUE8_(__VA_ARGS__)

// wait until <=CNT VMEM outstanding; "+v" ties the consumed fragments to
// this asm so MFMAs below cannot be hoisted above it (rule 18), plus an
// explicit sched_barrier.
#define WAIT8_(A0, A1, A2, A3, B0, B1, B2, B3, CNT)                          \
  asm volatile("s_waitcnt vmcnt(" CNT ")"                                    \
               : "+v"(A0), "+v"(A1), "+v"(A2), "+v"(A3),                     \
                 "+v"(B0), "+v"(B1), "+v"(B2), "+v"(B3)                      \
               :                                                             \
               : "memory");                                                  \
  __builtin_amdgcn_sched_barrier(0)
#define WAIT8(...) WAIT8_(__VA_ARGS__)

// one 16x16 output fragment x K=64: two chained MFMAs
#define MM(AF, BF, MI, NI)                                                                        \
  acc[MI][NI] = __builtin_amdgcn_mfma_f32_16x16x32_fp8_fp8((AF)[0], (BF)[0], acc[MI][NI], 0, 0, 0); \
  acc[MI][NI] = __builtin_amdgcn_mfma_f32_16x16x32_fp8_fp8((AF)[1], (BF)[1], acc[MI][NI], 0, 0, 0)

// 32 MFMAs: full 64x64 tile x one 64B k-slice
#define MFMA32_(A0, A1, A2, A3, B0, B1, B2, B3)                              \
  do {                                                                       \
    MM(A0, B0, 0, 0); MM(A0, B1, 0, 1); MM(A0, B2, 0, 2); MM(A0, B3, 0, 3);  \
    MM(A1, B0, 1, 0); MM(A1, B1, 1, 1); MM(A1, B2, 1, 2); MM(A1, B3, 1, 3);  \
    MM(A2, B0, 2, 0); MM(A2, B1, 2, 1); MM(A2, B2, 2, 2); MM(A2, B3, 2, 3);  \
    MM(A3, B0, 3, 0); MM(A3, B1, 3, 1); MM(A3, B2, 3, 2); MM(A3, B3, 3, 3);  \
  } while (0)
#define MFMA32(...) MFMA32_(__VA_ARGS__)

// steady-state step: issue the set 2 steps ahead, wait for the oldest
// in-flight batch (24 outstanding -> vmcnt(16)), compute on it.
#define STEP3_(IA0, IA1, IA2, IA3, IB0, IB1, IB2, IB3,                       \
               UA0, UA1, UA2, UA3, UB0, UB1, UB2, UB3, PA, PB)               \
  ISSUE8_(IA0, IA1, IA2, IA3, IB0, IB1, IB2, IB3, PA, PB);                   \
  WAIT8_(UA0, UA1, UA2, UA3, UB0, UB1, UB2, UB3, "16");                      \
  MFMA32_(UA0, UA1, UA2, UA3, UB0, UB1, UB2, UB3)
#define STEP3(...) STEP3_(__VA_ARGS__)

#define SET_P aP0, aP1, aP2, aP3, bP0, bP1, bP2, bP3
#define SET_Q aQ0, aQ1, aQ2, aQ3, bQ0, bQ1, bQ2, bQ3
#define SET_R aR0, aR1, aR2, aR3, bR0, bR1, bR2, bR3

// Upper-triangular fused Gram+RBF+reductions. 520 blocks of 256 threads =
// 4 independent waves, each owning one 64x64 tile; operands read directly
// from fragment-major global via the asm-pinned depth-3 pipeline.
__launch_bounds__(256, 2)
__global__ void hsic_main(const unsigned char* __restrict__ Xf8,
                          const unsigned char* __restrict__ Yf8,
                          const float* __restrict__ sqX, const float* __restrict__ sqY,
                          float* __restrict__ sX, float* __restrict__ sY,
                          float* __restrict__ T1) {
  const int tid = threadIdx.x;
  const int lane = tid & 63, wave = tid >> 6;

  // XCD-contiguous segment swizzle at block level; 4 consecutive tile
  // indices per block (one per wave). Bijection on [0,2080) (R18-verified):
  const int b = blockIdx.x;
  const int idx = (b & 7) * (NBLK / 8) + (b >> 3) * 4 + wave;

  // triangular decode: idx -> (bI, bJ) with bJ >= bI (row-major triangle)
  const float nf = (float)NB + 0.5f;
  int bI = (int)(nf - sqrtf(nf * nf - 2.0f * (float)idx));
  if (bI < 0) bI = 0;
  if (bI >= NB) bI = NB - 1;
  while (bI * NB - bI * (bI - 1) / 2 > idx) --bI;
  while ((bI + 1) * NB - (bI + 1) * bI / 2 <= idx) ++bI;
  const int bJ = bI + (idx - (bI * NB - bI * (bI - 1) / 2));
  const bool offdiag = (bI != bJ);

  const int quad = lane >> 4, cl = lane & 15;
  const int lane16 = lane << 4;

  // per-lane tile base addresses (fragment siblings via offset immediates,
  // k-slice advance +TILEB added in C)
  const unsigned char* pAx = Xf8 + (size_t)bI * PANELB + lane16;
  const unsigned char* pBx = Xf8 + (size_t)bJ * PANELB + lane16;
  const unsigned char* pAy = Yf8 + (size_t)bI * PANELB + lane16;
  const unsigned char* pBy = Yf8 + (size_t)bJ * PANELB + lane16;

  floatx4 acc[4][4];
#pragma unroll
  for (int i = 0; i < 4; ++i)
#pragma unroll
    for (int j = 0; j < 4; ++j) acc[i][j] = (floatx4){0.f, 0.f, 0.f, 0.f};

  const int Ib = bI * BM;
  const int Jb = bJ * BM;

  // X-phase results carried into the Y epilogue:
  unsigned int kxp[4][4][2];   // kx packed as bf16 pairs (exact for 0/1)
  unsigned int fmask = 0;      // per-fragment wave-uniform "kx nonzero" bits
  float t1l = 0.f;

  longx2 SET_P, SET_Q, SET_R;

  // ---- X phase: depth-3, fully unrolled ----
  ISSUE8(SET_P, pAx + 0 * TILEB, pBx + 0 * TILEB);            // P <- x0
  ISSUE8(SET_Q, pAx + 1 * TILEB, pBx + 1 * TILEB);            // Q <- x1
  STEP3(SET_R, SET_P, pAx + 2 * TILEB, pBx + 2 * TILEB);      // s0: R<-x2, use x0
  STEP3(SET_P, SET_Q, pAx + 3 * TILEB, pBx + 3 * TILEB);      // s1: P<-x3, use x1
  STEP3(SET_Q, SET_R, pAx + 4 * TILEB, pBx + 4 * TILEB);      // s2: Q<-x4, use x2
  STEP3(SET_R, SET_P, pAx + 5 * TILEB, pBx + 5 * TILEB);      // s3: R<-x5, use x3
  STEP3(SET_P, SET_Q, pAx + 6 * TILEB, pBx + 6 * TILEB);      // s4: P<-x6, use x4
  STEP3(SET_Q, SET_R, pAx + 7 * TILEB, pBx + 7 * TILEB);      // s5: Q<-x7, use x5
  STEP3(SET_R, SET_P, pAy + 0 * TILEB, pBy + 0 * TILEB);      // s6: R<-y0, use x6
  STEP3(SET_P, SET_Q, pAy + 1 * TILEB, pBy + 1 * TILEB);      // s7: P<-y1, use x7

  // ---- X epilogue: acc -> kx; sX atomics; pack kx; reset acc ----
  // (foreign VMEM here is FIFO-newer than our outstanding R/P prefetch ->
  // compiler waits can only over-wait; correctness unaffected.)
  // C/D layout (m89): col = lane&15, row = quad*4 + reg
  {
    float rx[4][4];
    float cx[4];
#pragma unroll
    for (int mi = 0; mi < 4; ++mi)
#pragma unroll
      for (int r = 0; r < 4; ++r) rx[mi][r] = 0.f;
#pragma unroll
    for (int ni = 0; ni < 4; ++ni) cx[ni] = 0.f;

#pragma unroll
    for (int mi = 0; mi < 4; ++mi) {
      const int ig0 = Ib + mi * 16 + quad * 4;
      float sxi[4];
#pragma unroll
      for (int r = 0; r < 4; ++r) sxi[r] = sqX[ig0 + r];
#pragma unroll
      for (int ni = 0; ni < 4; ++ni) {
        const int jg = Jb + ni * 16 + cl;
        const float sxj = sqX[jg];
        float d2x[4];
        bool lflag = false;
#pragma unroll
        for (int r = 0; r < 4; ++r) {
          const int ig = ig0 + r;
          d2x[r] = sxi[r] + sxj - 2.f * acc[mi][ni][r];
          lflag |= (d2x[r] < D2_SKIP) | (ig == jg);
        }
        float kxv[4] = {0.f, 0.f, 0.f, 0.f};
        if (__any(lflag)) {   // wave-uniform; skipped frags are exactly 0
          fmask |= (1u << (mi * 4 + ni));
#pragma unroll
          for (int r = 0; r < 4; ++r) {
            const int ig = ig0 + r;
            kxv[r] = (ig == jg) ? 1.f : __expf(-0.5f * d2x[r]);
            rx[mi][r] += kxv[r];
            cx[ni] += kxv[r];
          }
        }
        kxp[mi][ni][0] = (unsigned)bf16bits(kxv[0]) | ((unsigned)bf16bits(kxv[1]) << 16);
        kxp[mi][ni][1] = (unsigned)bf16bits(kxv[2]) | ((unsigned)bf16bits(kxv[3]) << 16);
        // reset acc for the Y phase
        acc[mi][ni] = (floatx4){0.f, 0.f, 0.f, 0.f};
      }
    }

    if (fmask != 0) {
      // row sums: reduce across the 16 columns (lanes cl=0..15 per quad)
#pragma unroll
      for (int mi = 0; mi < 4; ++mi)
#pragma unroll
        for (int r = 0; r < 4; ++r) {
          float vx = rx[mi][r];
#pragma unroll
          for (int mm = 1; mm < 16; mm <<= 1) vx += __shfl_xor(vx, mm, 16);
          rx[mi][r] = vx;
        }
      if (cl == 0) {
#pragma unroll
        for (int mi = 0; mi < 4; ++mi)
#pragma unroll
          for (int r = 0; r < 4; ++r)
            atomicAdd(&sX[Ib + mi * 16 + quad * 4 + r], rx[mi][r]);
      }
      if (offdiag) {
#pragma unroll
        for (int ni = 0; ni < 4; ++ni) {
          float vx = cx[ni];
          vx += __shfl_xor(vx, 16, 64);
          vx += __shfl_xor(vx, 32, 64);
          if (quad == 0) atomicAdd(&sX[Jb + ni * 16 + cl], vx);
        }
      }
    }
  }

  // ---- Y phase (y0 in R, y1 in P, both possibly still in flight) ----
  STEP3(SET_Q, SET_R, pAy + 2 * TILEB, pBy + 2 * TILEB);      // s8:  Q<-y2, use y0
  STEP3(SET_R, SET_P, pAy + 3 * TILEB, pBy + 3 * TILEB);      // s9:  R<-y3, use y1
  STEP3(SET_P, SET_Q, pAy + 4 * TILEB, pBy + 4 * TILEB);      // s10: P<-y4, use y2
  STEP3(SET_Q, SET_R, pAy + 5 * TILEB, pBy + 5 * TILEB);      // s11: Q<-y5, use y3
  STEP3(SET_R, SET_P, pAy + 6 * TILEB, pBy + 6 * TILEB);      // s12: R<-y6, use y4
  STEP3(SET_P, SET_Q, pAy + 7 * TILEB, pBy + 7 * TILEB);      // s13: P<-y7, use y5
  WAIT8(SET_R, "8");                                          // s14: use y6
  MFMA32(SET_R);
  WAIT8(SET_P, "0");                                          // s15: use y7 (drain)
  MFMA32(SET_P);

  // ---- Y epilogue ----
  {
    float ry[4][4];
    float cy[4];
    bool anyy = false;
#pragma unroll
    for (int mi = 0; mi < 4; ++mi)
#pragma unroll
      for (int r = 0; r < 4; ++r) ry[mi][r] = 0.f;
#pragma unroll
    for (int ni = 0; ni < 4; ++ni) cy[ni] = 0.f;

#pragma unroll
    for (int mi = 0; mi < 4; ++mi) {
      const int ig0 = Ib + mi * 16 + quad * 4;
      float syi[4];
#pragma unroll
      for (int r = 0; r < 4; ++r) syi[r] = sqY[ig0 + r];
#pragma unroll
      for (int ni = 0; ni < 4; ++ni) {
        const int jg = Jb + ni * 16 + cl;
        const float syj = sqY[jg];
        float d2y[4];
        bool lflag = false;
#pragma unroll
        for (int r = 0; r < 4; ++r) {
          const int ig = ig0 + r;
          d2y[r] = syi[r] + syj - 2.f * acc[mi][ni][r];
          lflag |= (d2y[r] < D2_SKIP) | (ig == jg);
        }
        const bool xb = (fmask >> (mi * 4 + ni)) & 1u;  // wave-uniform
        if (__any(lflag) || xb) {
          anyy = true;
          float kyv[4];
#pragma unroll
          for (int r = 0; r < 4; ++r) {
            const int ig = ig0 + r;
            kyv[r] = (ig == jg) ? 1.f : __expf(-0.5f * d2y[r]);
            ry[mi][r] += kyv[r];
            cy[ni] += kyv[r];
          }
          if (xb) {
            const float kx0 = __builtin_bit_cast(float, (kxp[mi][ni][0] & 0xFFFFu) << 16);
            const float kx1 = __builtin_bit_cast(float, kxp[mi][ni][0] & 0xFFFF0000u);
            const float kx2 = __builtin_bit_cast(float, (kxp[mi][ni][1] & 0xFFFFu) << 16);
            const float kx3 = __builtin_bit_cast(float, kxp[mi][ni][1] & 0xFFFF0000u);
            t1l += kx0 * kyv[0] + kx1 * kyv[1] + kx2 * kyv[2] + kx3 * kyv[3];
          }
        }
      }
    }

    if (anyy) {
#pragma unroll
      for (int mi = 0; mi < 4; ++mi)
#pragma unroll
        for (int r = 0; r < 4; ++r) {
          float vy = ry[mi][r];
#pragma unroll
          for (int mm = 1; mm < 16; mm <<= 1) vy += __shfl_xor(vy, mm, 16);
          ry[mi][r] = vy;
        }
      if (cl == 0) {
#pragma unroll
        for (int mi = 0; mi < 4; ++mi)
#pragma unroll
          for (int r = 0; r < 4; ++r)
            atomicAdd(&sY[Ib + mi * 16 + quad * 4 + r], ry[mi][r]);
      }
      if (offdiag) {
#pragma unroll
        for (int ni = 0; ni < 4; ++ni) {
          float vy = cy[ni];
          vy += __shfl_xor(vy, 16, 64);
          vy += __shfl_xor(vy, 32, 64);
          if (quad == 0) atomicAdd(&sY[Jb + ni * 16 + cl], vy);
        }
      }
    }
  }

  // T1 wave reduction (off-diagonal tiles count twice by symmetry)
  if (fmask != 0) {
    t1l *= offdiag ? 2.f : 1.f;
#pragma unroll
    for (int mm = 1; mm < 64; mm <<= 1) t1l += __shfl_xor(t1l, mm, 64);
    if (lane == 0 && t1l != 0.f) atomicAdd(T1, t1l);
  }
}

// hsic = (T1 - (2/n) sum sX_i sY_i + (SX*SY)/n^2) / (n-1)^2
__global__ void final_kernel(const float* __restrict__ sX, const float* __restrict__ sY,
                             const float* __restrict__ T1, float* __restrict__ out) {
  const int tid = threadIdx.x;
  float dp = 0.f, sa = 0.f, sb = 0.f;
  for (int i = tid * 4; i < N; i += 1024) {
    const float4 a4 = *(const float4*)&sX[i];
    const float4 b4 = *(const float4*)&sY[i];
    dp += a4.x * b4.x + a4.y * b4.y + a4.z * b4.z + a4.w * b4.w;
    sa += a4.x + a4.y + a4.z + a4.w;
    sb += b4.x + b4.y + b4.z + b4.w;
  }
#pragma unroll
  for (int mm = 1; mm < 64; mm <<= 1) {
    dp += __shfl_xor(dp, mm, 64);
    sa += __shfl_xor(sa, mm, 64);
    sb += __shfl_xor(sb, mm, 64);
  }
  __shared__ float r0[4], r1[4], r2[4];
  if ((tid & 63) == 0) { int w = tid >> 6; r0[w] = dp; r1[w] = sa; r2[w] = sb; }
  __syncthreads();
  if (tid == 0) {
    dp = r0[0] + r0[1] + r0[2] + r0[3];
    sa = r1[0] + r1[1] + r1[2] + r1[3];
    sb = r2[0] + r2[1] + r2[2] + r2[3];
    const float n = (float)N;
    const float total = T1[0] - (2.f / n) * dp + (sa * sb) / (n * n);
    out[0] = total / ((n - 1.f) * (n - 1.f));
  }
}

}  // namespace

extern "C" void kernel_launch(void* const* d_in, const int* in_sizes, int n_in,
                              void* d_out, int out_size, void* d_ws, size_t ws_size,
                              hipStream_t stream) {
  const float* X = (const float*)d_in[0];
  const float* Y = (const float*)d_in[1];
  char* ws = (char*)d_ws;
  if (ws_size < WS_NEED) return;

  unsigned char* Xf8 = (unsigned char*)(ws + OFF_XB);
  unsigned char* Yf8 = (unsigned char*)(ws + OFF_YB);
  float* sqX = (float*)(ws + OFF_SQX);
  float* sqY = (float*)(ws + OFF_SQY);
  float* sX  = (float*)(ws + OFF_SX);
  float* sY  = (float*)(ws + OFF_SY);
  float* T1  = (float*)(ws + OFF_T1);
  float* out = (float*)d_out;

  prep_kernel<<<dim3(N / 4, 2), 256, 0, stream>>>(X, Y, Xf8, Yf8, sqX, sqY, sX, sY, T1);
  hsic_main<<<NGRID, 256, 0, stream>>>(Xf8, Yf8, sqX, sqY, sX, sY, T1);
  final_kernel<<<1, 256, 0, stream>>>(sX, sY, T1, out);
}

// Round 12
// 90.902 us; speedup vs baseline: 1.0203x; 1.0203x over previous
//
#include <hip/hip_runtime.h>
#include <hip/hip_bf16.h>

namespace {

constexpr int N = 4096;
constexpr int D = 512;
constexpr int BM = 64;    // block tile 64x64; 2080 blocks, 2x2 waves of 32x32
constexpr int BK = 64;    // K-step per fragment column-slice (64 fp8 bytes)
constexpr int KITERS = D / BK;  // 8 per phase
constexpr int NB = N / BM;      // 64 block-rows
constexpr int NBLK = NB * (NB + 1) / 2;  // 2080 upper-tri tiles (= 8 * 260)
constexpr int TILEB = BM * BK;  // 4 KB: one 64-row x 64-byte k-slice
constexpr int PANELB = BM * D;  // 32 KB: one 64-row fp8 panel

// workspace layout (bytes)
constexpr size_t OFF_XB  = 0;                          // fp8 X  [N*D]  fragment-major
constexpr size_t OFF_YB  = (size_t)N * D;              // fp8 Y  [N*D]  fragment-major
constexpr size_t OFF_SQX = OFF_YB + (size_t)N * D;     // fp32 ||x_i||^2 [N]
constexpr size_t OFF_SQY = OFF_SQX + (size_t)N * 4;
constexpr size_t OFF_SX  = OFF_SQY + (size_t)N * 4;    // fp32 row sums KX [N]
constexpr size_t OFF_SY  = OFF_SX + (size_t)N * 4;     // fp32 row sums KY [N]
constexpr size_t OFF_T1  = OFF_SY + (size_t)N * 4;     // fp32 scalar sum(KX*KY)
constexpr size_t WS_NEED = OFF_T1 + 4;

// FRAGMENT-MAJOR ws layout: element (row r, k) of a 64x64B slice lives at
//   nib*1024 + quad*256 + cl*16 + pass*8 + j
// with nib=(r>>4)&3, cl=r&15, quad=(k>>3)&3, pass=k>>5, j=k&7.
// An MFMA operand fragment (16 rows x 64B of K) is a CONTIGUOUS 1KB at
// fragment base + lane*16 -- one coalesced global_load_dwordx4 per lane.
//
// R24 = R22b VERBATIM (champion restore, 91.09us measured).
// Session evidence: main is wall-ed at ~35+-3us across SIX structures
// (LDS+barrier R14/15; compiler direct R16; asm depth-2 R22b; asm depth-3
// 64x64/wave R23) spanning 4x VMEM bytes, 1-4 waves/SIMD, compiler vs asm
// scheduling. No model (latency/BW/issue-rate) fits all rows; further
// structural mutation has ~zero EV. R23 (92.75 cold ~= 91 warm) did not
// beat this kernel -> restore it.
// Known-bad directions (measured): launch_bounds caps (R19 spill 233us,
// R20 AGPR 185us, R21 fused-tail 167us + VGPR48); 64-thread blocks (R17
// 92us); fused final via device counter (R21: perturbs loop regalloc).
constexpr float D2_SKIP = 240.f;

typedef __attribute__((ext_vector_type(4))) float floatx4;
typedef __attribute__((ext_vector_type(2))) long longx2;

__device__ inline unsigned short bf16bits(float f) {
  return __builtin_bit_cast(unsigned short, __float2bfloat16(f));
}

// fp32 -> fp8 e4m3 (OCP) conversion into the fragment-major layout + exact
// fp32 row squared norms. One wave per row; lane handles 8 consecutive
// elements -> one 8B store. Also zeroes sX/sY/T1.
__global__ void prep_kernel(const float* __restrict__ X, const float* __restrict__ Y,
                            unsigned char* __restrict__ Xf8, unsigned char* __restrict__ Yf8,
                            float* __restrict__ sqX, float* __restrict__ sqY,
                            float* __restrict__ sX, float* __restrict__ sY,
                            float* __restrict__ T1) {
  const int wave = threadIdx.x >> 6, lane = threadIdx.x & 63;
  const int row = blockIdx.x * 4 + wave;
  const int m = blockIdx.y;
  const float* __restrict__ src = m ? Y : X;
  unsigned char* __restrict__ dst = m ? Yf8 : Xf8;
  float* __restrict__ dsq = m ? sqY : sqX;

  if (threadIdx.x < 4) {
    float* z = m ? sY : sX;
    z[blockIdx.x * 4 + threadIdx.x] = 0.f;
  }
  if (blockIdx.x == 0 && m == 0 && threadIdx.x == 0) *T1 = 0.f;

  const float4* s4 = (const float4*)(src + (size_t)row * D);
  float4 v0 = s4[lane * 2];
  float4 v1 = s4[lane * 2 + 1];
  float acc = v0.x * v0.x + v0.y * v0.y + v0.z * v0.z + v0.w * v0.w
            + v1.x * v1.x + v1.y * v1.y + v1.z * v1.z + v1.w * v1.w;

  unsigned int w0 = 0, w1 = 0;
  w0 = __builtin_amdgcn_cvt_pk_fp8_f32(v0.x, v0.y, w0, false);
  w0 = __builtin_amdgcn_cvt_pk_fp8_f32(v0.z, v0.w, w0, true);
  w1 = __builtin_amdgcn_cvt_pk_fp8_f32(v1.x, v1.y, w1, false);
  w1 = __builtin_amdgcn_cvt_pk_fp8_f32(v1.z, v1.w, w1, true);
  const unsigned long long pk =
      (unsigned long long)w0 | ((unsigned long long)w1 << 32);

  // destination: k = lane*8 .. +8 of this row, fragment-major address
  const int p    = row >> 6;          // 64-row panel
  const int nib  = (row >> 4) & 3;
  const int cl   = row & 15;
  const int ks   = lane >> 3;         // 64-byte k-slice
  const int pass = (lane >> 2) & 1;
  const int quad = lane & 3;
  const size_t off = (size_t)p * PANELB + (size_t)ks * TILEB +
                     nib * 1024 + quad * 256 + cl * 16 + pass * 8;
  *(unsigned long long*)(dst + off) = pk;

#pragma unroll
  for (int mm = 32; mm >= 1; mm >>= 1) acc += __shfl_xor(acc, mm, 64);
  if (lane == 0) dsq[row] = acc;
}

// --- asm pipeline primitives -------------------------------------------
// 4 async 16B loads via 64-bit VGPR addresses:
//   A0 <- [PA], A1 <- [PA+1024], B0 <- [PB], B1 <- [PB+1024]
#define ISSUE4(A0, A1, B0, B1, PA, PB)                                       \
  asm volatile("global_load_dwordx4 %0, %4, off\n\t"                         \
               "global_load_dwordx4 %1, %4, off offset:1024\n\t"             \
               "global_load_dwordx4 %2, %5, off\n\t"                         \
               "global_load_dwordx4 %3, %5, off offset:1024"                 \
               : "=&v"(A0), "=&v"(A1), "=&v"(B0), "=&v"(B1)                  \
               : "v"(PA), "v"(PB)                                            \
               : "memory")

// wait until <=CNT VMEM outstanding; "+v" ties the consumed fragments to
// this asm so the MFMAs below cannot be scheduled above it (rule 18), plus
// an explicit sched_barrier.
#define WAIT4(A0, A1, B0, B1, CNT)                                           \
  asm volatile("s_waitcnt vmcnt(" CNT ")"                                    \
               : "+v"(A0), "+v"(A1), "+v"(B0), "+v"(B1)                      \
               :                                                             \
               : "memory");                                                  \
  __builtin_amdgcn_sched_barrier(0)

// 16 MFMAs in R16's exact order: (mi,ni) = (0,0),(0,1),(1,0),(1,1), two
// k-halves each -> bit-identical accumulation.
#define MFMA_SET(A0, A1, B0, B1)                                                                  \
  do {                                                                                            \
    acc[0][0] = __builtin_amdgcn_mfma_f32_16x16x32_fp8_fp8((A0)[0], (B0)[0], acc[0][0], 0, 0, 0); \
    acc[0][0] = __builtin_amdgcn_mfma_f32_16x16x32_fp8_fp8((A0)[1], (B0)[1], acc[0][0], 0, 0, 0); \
    acc[0][1] = __builtin_amdgcn_mfma_f32_16x16x32_fp8_fp8((A0)[0], (B1)[0], acc[0][1], 0, 0, 0); \
    acc[0][1] = __builtin_amdgcn_mfma_f32_16x16x32_fp8_fp8((A0)[1], (B1)[1], acc[0][1], 0, 0, 0); \
    acc[1][0] = __builtin_amdgcn_mfma_f32_16x16x32_fp8_fp8((A1)[0], (B0)[0], acc[1][0], 0, 0, 0); \
    acc[1][0] = __builtin_amdgcn_mfma_f32_16x16x32_fp8_fp8((A1)[1], (B0)[1], acc[1][0], 0, 0, 0); \
    acc[1][1] = __builtin_amdgcn_mfma_f32_16x16x32_fp8_fp8((A1)[0], (B1)[0], acc[1][1], 0, 0, 0); \
    acc[1][1] = __builtin_amdgcn_mfma_f32_16x16x32_fp8_fp8((A1)[1], (B1)[1], acc[1][1], 0, 0, 0); \
  } while (0)

// one steady-state step: issue set(k+1) into I* from addresses PA/PB, wait
// for U* (the 4 newest in flight are I*), compute on U*.
#define STEP(IA0, IA1, IB0, IB1, UA0, UA1, UB0, UB1, PA, PB)                 \
  ISSUE4(IA0, IA1, IB0, IB1, PA, PB);                                        \
  WAIT4(UA0, UA1, UB0, UB1, "4");                                            \
  MFMA_SET(UA0, UA1, UB0, UB1)

// Upper-triangular fused Gram+RBF+reductions. 2080 blocks of 256 threads;
// 2x2 waves of 32x32 per 64x64 tile; operands read directly from the
// fragment-major global buffers via the asm-pinned depth-2 pipeline.
__launch_bounds__(256, 4)
__global__ void hsic_main(const unsigned char* __restrict__ Xf8,
                          const unsigned char* __restrict__ Yf8,
                          const float* __restrict__ sqX, const float* __restrict__ sqY,
                          float* __restrict__ sX, float* __restrict__ sY,
                          float* __restrict__ T1) {
  // XCD-contiguous segment swizzle (bijection on [0,2080): 2080 = 8*260)
  const int b = blockIdx.x;
  int idx = (b & 7) * (NBLK / 8) + (b >> 3);

  // triangular decode: idx -> (bI, bJ) with bJ >= bI (row-major triangle)
  const float nf = (float)NB + 0.5f;
  int bI = (int)(nf - sqrtf(nf * nf - 2.0f * (float)idx));
  if (bI < 0) bI = 0;
  if (bI >= NB) bI = NB - 1;
  while (bI * NB - bI * (bI - 1) / 2 > idx) --bI;
  while ((bI + 1) * NB - (bI + 1) * bI / 2 <= idx) ++bI;
  const int bJ = bI + (idx - (bI * NB - bI * (bI - 1) / 2));
  const bool offdiag = (bI != bJ);

  const int tid = threadIdx.x;
  const int lane = tid & 63, wave = tid >> 6;
  const int wm = wave >> 1, wn = wave & 1;   // 2x2 wave grid, each wave 32x32
  const int quad = lane >> 4, cl = lane & 15;
  const int lane16 = lane << 4;

  // per-lane fragment addresses (the +1024 sibling folds into the asm's
  // offset immediate; the k-slice advance is +TILEB per step, added in C)
  const unsigned char* pAx = Xf8 + (size_t)bI * PANELB + wm * 2048 + lane16;
  const unsigned char* pBx = Xf8 + (size_t)bJ * PANELB + wn * 2048 + lane16;
  const unsigned char* pAy = Yf8 + (size_t)bI * PANELB + wm * 2048 + lane16;
  const unsigned char* pBy = Yf8 + (size_t)bJ * PANELB + wn * 2048 + lane16;

  floatx4 acc[2][2];
#pragma unroll
  for (int i = 0; i < 2; ++i)
#pragma unroll
    for (int j = 0; j < 2; ++j) acc[i][j] = (floatx4){0.f, 0.f, 0.f, 0.f};

  const int Ib = bI * BM + wm * 32;
  const int Jb = bJ * BM + wn * 32;

  // X-phase results carried into the Y epilogue:
  unsigned int kxp[2][2][2];   // kx packed as bf16 pairs (exact for 0/1)
  unsigned int fmask = 0;      // per-fragment wave-uniform "kx nonzero" bits
  float t1l = 0.f;

  longx2 aP0, aP1, bP0, bP1, aQ0, aQ1, bQ0, bQ1;

  // ---- X phase: depth-2 pipeline, fully unrolled ----
  ISSUE4(aP0, aP1, bP0, bP1, pAx + 0 * TILEB, pBx + 0 * TILEB);                      // P <- X0
  STEP(aQ0, aQ1, bQ0, bQ1, aP0, aP1, bP0, bP1, pAx + 1 * TILEB, pBx + 1 * TILEB);   // k0
  STEP(aP0, aP1, bP0, bP1, aQ0, aQ1, bQ0, bQ1, pAx + 2 * TILEB, pBx + 2 * TILEB);   // k1
  STEP(aQ0, aQ1, bQ0, bQ1, aP0, aP1, bP0, bP1, pAx + 3 * TILEB, pBx + 3 * TILEB);   // k2
  STEP(aP0, aP1, bP0, bP1, aQ0, aQ1, bQ0, bQ1, pAx + 4 * TILEB, pBx + 4 * TILEB);   // k3
  STEP(aQ0, aQ1, bQ0, bQ1, aP0, aP1, bP0, bP1, pAx + 5 * TILEB, pBx + 5 * TILEB);   // k4
  STEP(aP0, aP1, bP0, bP1, aQ0, aQ1, bQ0, bQ1, pAx + 6 * TILEB, pBx + 6 * TILEB);   // k5
  STEP(aQ0, aQ1, bQ0, bQ1, aP0, aP1, bP0, bP1, pAx + 7 * TILEB, pBx + 7 * TILEB);   // k6
  STEP(aP0, aP1, bP0, bP1, aQ0, aQ1, bQ0, bQ1, pAy + 0 * TILEB, pBy + 0 * TILEB);   // k7: prefetch Y0

  // ---- X epilogue: acc -> kx; sX atomics; pack kx; reset acc ----
  // (compiler VMEM here is FIFO-newer than our outstanding P prefetch,
  // so its conservative waitcnts remain correct.)
  // C/D layout (m89): col = lane&15, row = quad*4 + reg
  {
    float rx[2][4];
    float cx[2];
#pragma unroll
    for (int mi = 0; mi < 2; ++mi)
#pragma unroll
      for (int r = 0; r < 4; ++r) rx[mi][r] = 0.f;
#pragma unroll
    for (int ni = 0; ni < 2; ++ni) cx[ni] = 0.f;

#pragma unroll
    for (int mi = 0; mi < 2; ++mi) {
      const int ig0 = Ib + mi * 16 + quad * 4;
      float sxi[4];
#pragma unroll
      for (int r = 0; r < 4; ++r) sxi[r] = sqX[ig0 + r];
#pragma unroll
      for (int ni = 0; ni < 2; ++ni) {
        const int jg = Jb + ni * 16 + cl;
        const float sxj = sqX[jg];
        float d2x[4];
        bool lflag = false;
#pragma unroll
        for (int r = 0; r < 4; ++r) {
          const int ig = ig0 + r;
          d2x[r] = sxi[r] + sxj - 2.f * acc[mi][ni][r];
          lflag |= (d2x[r] < D2_SKIP) | (ig == jg);
        }
        float kxv[4] = {0.f, 0.f, 0.f, 0.f};
        if (__any(lflag)) {   // wave-uniform; skipped frags are exactly 0
          fmask |= (1u << (mi * 2 + ni));
#pragma unroll
          for (int r = 0; r < 4; ++r) {
            const int ig = ig0 + r;
            kxv[r] = (ig == jg) ? 1.f : __expf(-0.5f * d2x[r]);
            rx[mi][r] += kxv[r];
            cx[ni] += kxv[r];
          }
        }
        kxp[mi][ni][0] = (unsigned)bf16bits(kxv[0]) | ((unsigned)bf16bits(kxv[1]) << 16);
        kxp[mi][ni][1] = (unsigned)bf16bits(kxv[2]) | ((unsigned)bf16bits(kxv[3]) << 16);
        // reset acc for the Y phase
        acc[mi][ni] = (floatx4){0.f, 0.f, 0.f, 0.f};
      }
    }

    if (fmask != 0) {
      // row sums: reduce across the 16 columns (lanes cl=0..15 per quad)
#pragma unroll
      for (int mi = 0; mi < 2; ++mi)
#pragma unroll
        for (int r = 0; r < 4; ++r) {
          float vx = rx[mi][r];
#pragma unroll
          for (int mm = 1; mm < 16; mm <<= 1) vx += __shfl_xor(vx, mm, 16);
          rx[mi][r] = vx;
        }
      if (cl == 0) {
#pragma unroll
        for (int mi = 0; mi < 2; ++mi)
#pragma unroll
          for (int r = 0; r < 4; ++r)
            atomicAdd(&sX[Ib + mi * 16 + quad * 4 + r], rx[mi][r]);
      }
      if (offdiag) {
#pragma unroll
        for (int ni = 0; ni < 2; ++ni) {
          float vx = cx[ni];
          vx += __shfl_xor(vx, 16, 64);
          vx += __shfl_xor(vx, 32, 64);
          if (quad == 0) atomicAdd(&sX[Jb + ni * 16 + cl], vx);
        }
      }
    }
  }

  // ---- Y phase (Y0 already in flight in P) ----
  STEP(aQ0, aQ1, bQ0, bQ1, aP0, aP1, bP0, bP1, pAy + 1 * TILEB, pBy + 1 * TILEB);   // y0
  STEP(aP0, aP1, bP0, bP1, aQ0, aQ1, bQ0, bQ1, pAy + 2 * TILEB, pBy + 2 * TILEB);   // y1
  STEP(aQ0, aQ1, bQ0, bQ1, aP0, aP1, bP0, bP1, pAy + 3 * TILEB, pBy + 3 * TILEB);   // y2
  STEP(aP0, aP1, bP0, bP1, aQ0, aQ1, bQ0, bQ1, pAy + 4 * TILEB, pBy + 4 * TILEB);   // y3
  STEP(aQ0, aQ1, bQ0, bQ1, aP0, aP1, bP0, bP1, pAy + 5 * TILEB, pBy + 5 * TILEB);   // y4
  STEP(aP0, aP1, bP0, bP1, aQ0, aQ1, bQ0, bQ1, pAy + 6 * TILEB, pBy + 6 * TILEB);   // y5
  STEP(aQ0, aQ1, bQ0, bQ1, aP0, aP1, bP0, bP1, pAy + 7 * TILEB, pBy + 7 * TILEB);   // y6
  WAIT4(aQ0, aQ1, bQ0, bQ1, "0");                                                   // y7: drain
  MFMA_SET(aQ0, aQ1, bQ0, bQ1);

  // ---- Y epilogue ----
  {
    float ry[2][4];
    float cy[2];
    bool anyy = false;
#pragma unroll
    for (int mi = 0; mi < 2; ++mi)
#pragma unroll
      for (int r = 0; r < 4; ++r) ry[mi][r] = 0.f;
#pragma unroll
    for (int ni = 0; ni < 2; ++ni) cy[ni] = 0.f;

#pragma unroll
    for (int mi = 0; mi < 2; ++mi) {
      const int ig0 = Ib + mi * 16 + quad * 4;
      float syi[4];
#pragma unroll
      for (int r = 0; r < 4; ++r) syi[r] = sqY[ig0 + r];
#pragma unroll
      for (int ni = 0; ni < 2; ++ni) {
        const int jg = Jb + ni * 16 + cl;
        const float syj = sqY[jg];
        float d2y[4];
        bool lflag = false;
#pragma unroll
        for (int r = 0; r < 4; ++r) {
          const int ig = ig0 + r;
          d2y[r] = syi[r] + syj - 2.f * acc[mi][ni][r];
          lflag |= (d2y[r] < D2_SKIP) | (ig == jg);
        }
        const bool xb = (fmask >> (mi * 2 + ni)) & 1u;  // wave-uniform
        if (__any(lflag) || xb) {
          anyy = true;
          float kyv[4];
#pragma unroll
          for (int r = 0; r < 4; ++r) {
            const int ig = ig0 + r;
            kyv[r] = (ig == jg) ? 1.f : __expf(-0.5f * d2y[r]);
            ry[mi][r] += kyv[r];
            cy[ni] += kyv[r];
          }
          if (xb) {
            const float kx0 = __builtin_bit_cast(float, (kxp[mi][ni][0] & 0xFFFFu) << 16);
            const float kx1 = __builtin_bit_cast(float, kxp[mi][ni][0] & 0xFFFF0000u);
            const float kx2 = __builtin_bit_cast(float, (kxp[mi][ni][1] & 0xFFFFu) << 16);
            const float kx3 = __builtin_bit_cast(float, kxp[mi][ni][1] & 0xFFFF0000u);
            t1l += kx0 * kyv[0] + kx1 * kyv[1] + kx2 * kyv[2] + kx3 * kyv[3];
          }
        }
      }
    }

    if (anyy) {
#pragma unroll
      for (int mi = 0; mi < 2; ++mi)
#pragma unroll
        for (int r = 0; r < 4; ++r) {
          float vy = ry[mi][r];
#pragma unroll
          for (int mm = 1; mm < 16; mm <<= 1) vy += __shfl_xor(vy, mm, 16);
          ry[mi][r] = vy;
        }
      if (cl == 0) {
#pragma unroll
        for (int mi = 0; mi < 2; ++mi)
#pragma unroll
          for (int r = 0; r < 4; ++r)
            atomicAdd(&sY[Ib + mi * 16 + quad * 4 + r], ry[mi][r]);
      }
      if (offdiag) {
#pragma unroll
        for (int ni = 0; ni < 2; ++ni) {
          float vy = cy[ni];
          vy += __shfl_xor(vy, 16, 64);
          vy += __shfl_xor(vy, 32, 64);
          if (quad == 0) atomicAdd(&sY[Jb + ni * 16 + cl], vy);
        }
      }
    }
  }

  // T1 wave reduction (off-diagonal tiles count twice by symmetry)
  if (fmask != 0) {
    t1l *= offdiag ? 2.f : 1.f;
#pragma unroll
    for (int mm = 1; mm < 64; mm <<= 1) t1l += __shfl_xor(t1l, mm, 64);
    if (lane == 0 && t1l != 0.f) atomicAdd(T1, t1l);
  }
}

// hsic = (T1 - (2/n) sum sX_i sY_i + (SX*SY)/n^2) / (n-1)^2
__global__ void final_kernel(const float* __restrict__ sX, const float* __restrict__ sY,
                             const float* __restrict__ T1, float* __restrict__ out) {
  const int tid = threadIdx.x;
  float dp = 0.f, sa = 0.f, sb = 0.f;
  for (int i = tid * 4; i < N; i += 1024) {
    const float4 a4 = *(const float4*)&sX[i];
    const float4 b4 = *(const float4*)&sY[i];
    dp += a4.x * b4.x + a4.y * b4.y + a4.z * b4.z + a4.w * b4.w;
    sa += a4.x + a4.y + a4.z + a4.w;
    sb += b4.x + b4.y + b4.z + b4.w;
  }
#pragma unroll
  for (int mm = 1; mm < 64; mm <<= 1) {
    dp += __shfl_xor(dp, mm, 64);
    sa += __shfl_xor(sa, mm, 64);
    sb += __shfl_xor(sb, mm, 64);
  }
  __shared__ float r0[4], r1[4], r2[4];
  if ((tid & 63) == 0) { int w = tid >> 6; r0[w] = dp; r1[w] = sa; r2[w] = sb; }
  __syncthreads();
  if (tid == 0) {
    dp = r0[0] + r0[1] + r0[2] + r0[3];
    sa = r1[0] + r1[1] + r1[2] + r1[3];
    sb = r2[0] + r2[1] + r2[2] + r2[3];
    const float n = (float)N;
    const float total = T1[0] - (2.f / n) * dp + (sa * sb) / (n * n);
    out[0] = total / ((n - 1.f) * (n - 1.f));
  }
}

}  // namespace

extern "C" void kernel_launch(void* const* d_in, const int* in_sizes, int n_in,
                              void* d_out, int out_size, void* d_ws, size_t ws_size,
                              hipStream_t stream) {
  const float* X = (const float*)d_in[0];
  const float* Y = (const float*)d_in[1];
  char* ws = (char*)d_ws;
  if (ws_size < WS_NEED) return;

  unsigned char* Xf8 = (unsigned char*)(ws + OFF_XB);
  unsigned char* Yf8 = (unsigned char*)(ws + OFF_YB);
  float* sqX = (float*)(ws + OFF_SQX);
  float* sqY = (float*)(ws + OFF_SQY);
  float* sX  = (float*)(ws + OFF_SX);
  float* sY  = (float*)(ws + OFF_SY);
  float* T1  = (float*)(ws + OFF_T1);
  float* out = (float*)d_out;

  prep_kernel<<<dim3(N / 4, 2), 256, 0, stream>>>(X, Y, Xf8, Yf8, sqX, sqY, sX, sY, T1);
  hsic_main<<<NBLK, 256, 0, stream>>>(Xf8, Yf8, sqX, sqY, sX, sY, T1);
  final_kernel<<<1, 256, 0, stream>>>(sX, sY, T1, out);
}